// Round 4
// baseline (403.581 us; speedup 1.0000x reference)
//
#include <hip/hip_runtime.h>

#define C_DIM 256
#define NCODE 1024
#define RESCUE_MARGIN 0.3f

typedef __bf16 bf16x8 __attribute__((ext_vector_type(8)));
typedef unsigned short u16x8 __attribute__((ext_vector_type(8)));
typedef float f32x4 __attribute__((ext_vector_type(4)));

// ws layout (byte offsets, 256-aligned), total ~2.26 MB
#define WS_ENORM 0          // f32[1024]
#define WS_META  4096       // u32 rescue count
#define WS_RLIST 8192       // u32[32768]
#define WS_CODES 139264     // u32[32768] (bit31 = rescue flag)
#define WS_EHI   270336     // bf16[1024*256] as u16
#define WS_PB    794624     // float2[32768*4] (b1,b2) per (row, nb)
#define WS_PBI   1843200    // u32[32768*4]    i1      per (row, nb)

__device__ __forceinline__ unsigned short bf16rne(float x) {
    unsigned u = __float_as_uint(x);
    return (unsigned short)((u + 0x7FFFu + ((u >> 16) & 1u)) >> 16);
}
__device__ __forceinline__ void bf16split(float x, unsigned short& h, unsigned short& l) {
    unsigned u  = __float_as_uint(x);
    unsigned rh = (u + 0x7FFFu + ((u >> 16) & 1u)) & 0xFFFF0000u;
    float    lf = x - __uint_as_float(rh);
    h = (unsigned short)(rh >> 16);
    l = bf16rne(lf);
}

// ---------- prep: emb -> bf16 ehi, enorm (fp32), reset meta ----------
__global__ __launch_bounds__(256) void prep_kernel(const float* __restrict__ emb,
                                                   unsigned short* __restrict__ ehi,
                                                   float* __restrict__ enorm,
                                                   unsigned* __restrict__ meta) {
    int gid = blockIdx.x * 256 + threadIdx.x;
    if (gid == 0) meta[0] = 0u;
    int row = gid >> 6, lane = gid & 63;   // 1024 rows, one wave each
    float4 v = reinterpret_cast<const float4*>(emb)[(size_t)row * 64 + lane];
    uint2 hp;
    hp.x = (unsigned)bf16rne(v.x) | ((unsigned)bf16rne(v.y) << 16);
    hp.y = (unsigned)bf16rne(v.z) | ((unsigned)bf16rne(v.w) << 16);
    *reinterpret_cast<uint2*>(ehi + (size_t)row * 256 + lane * 4) = hp;
    float s = v.x * v.x + v.y * v.y + v.z * v.z + v.w * v.w;
    #pragma unroll
    for (int off = 32; off; off >>= 1) s += __shfl_xor(s, off, 64);
    if (lane == 0) enorm[row] = s;
}

// ---------- main: 2-pass split-A MFMA, per-(row,nb) top-2 ----------
// grid 1024 = 256 M-tiles x 4 N-blocks (nb = bid & 3 -> adjacent ids share z).
// 512 thr (8 waves); wave w owns rows r0 + w*16 .. +15. A (z hi/lo) in regs.
__global__ __launch_bounds__(512, 4) void vq_main_kernel(
    const float* __restrict__ z, const unsigned short* __restrict__ ehi,
    const float* __restrict__ enorm, float2* __restrict__ pb,
    unsigned* __restrict__ pbi) {
    __shared__ float enorm_s[256];
    const int t    = threadIdx.x;
    const int w    = t >> 6;
    const int lane = t & 63;
    const int lr   = lane & 15;
    const int lg   = lane >> 4;
    const int bid  = blockIdx.x;
    const int nb   = bid & 3;
    const long r0  = (long)(bid >> 2) * 128;
    const int  c0  = nb * 256;

    if (t < 256) enorm_s[t] = enorm[c0 + t];

    // load + split my z row share: 8 k-chunks x 8 elems
    const long myrow = r0 + w * 16 + lr;
    bf16x8 ah[8], al[8];
    #pragma unroll
    for (int kc = 0; kc < 8; ++kc) {
        const float* zp = z + myrow * C_DIM + kc * 32 + lg * 8;
        float4 v0 = *reinterpret_cast<const float4*>(zp);
        float4 v1 = *reinterpret_cast<const float4*>(zp + 4);
        float vs[8] = {v0.x, v0.y, v0.z, v0.w, v1.x, v1.y, v1.z, v1.w};
        u16x8 hv, lv;
        #pragma unroll
        for (int j = 0; j < 8; ++j) {
            unsigned short h, l;
            bf16split(vs[j], h, l);
            hv[j] = h; lv[j] = l;
        }
        ah[kc] = __builtin_bit_cast(bf16x8, hv);
        al[kc] = __builtin_bit_cast(bf16x8, lv);
    }
    __syncthreads();   // enorm_s ready

    float b1[4], b2[4]; unsigned i1[4];
    #pragma unroll
    for (int r = 0; r < 4; ++r) { b1[r] = 3.4e38f; b2[r] = 3.4e38f; i1[r] = 0; }

    const unsigned short* bbase = ehi + ((size_t)(c0 + lr)) * C_DIM + lg * 8;

    for (int cb = 0; cb < 4; ++cb) {
        f32x4 acc[4];
        #pragma unroll
        for (int nf = 0; nf < 4; ++nf) acc[nf] = (f32x4){0.f, 0.f, 0.f, 0.f};

        #pragma unroll
        for (int kc = 0; kc < 8; ++kc) {
            bf16x8 bh[4];
            #pragma unroll
            for (int nf = 0; nf < 4; ++nf)
                bh[nf] = *reinterpret_cast<const bf16x8*>(
                    bbase + ((size_t)(cb * 64 + nf * 16)) * C_DIM + kc * 32);
            #pragma unroll
            for (int nf = 0; nf < 4; ++nf)
                acc[nf] = __builtin_amdgcn_mfma_f32_16x16x32_bf16(ah[kc], bh[nf], acc[nf], 0, 0, 0);
            #pragma unroll
            for (int nf = 0; nf < 4; ++nf)
                acc[nf] = __builtin_amdgcn_mfma_f32_16x16x32_bf16(al[kc], bh[nf], acc[nf], 0, 0, 0);
        }

        // fold into per-lane top-2 (local codes ascend -> first-index ties)
        #pragma unroll
        for (int nf = 0; nf < 4; ++nf) {
            int   cl = cb * 64 + nf * 16 + lr;
            float en = enorm_s[cl];
            #pragma unroll
            for (int r = 0; r < 4; ++r) {
                float d = fmaf(-2.f, acc[nf][r], en);
                if (d < b1[r]) { b2[r] = b1[r]; b1[r] = d; i1[r] = (unsigned)cl; }
                else if (d < b2[r]) { b2[r] = d; }
            }
        }
    }

    // cross-lane top-2 merge over the 16 lanes (lr) sharing a row-group
    #pragma unroll
    for (int r = 0; r < 4; ++r) {
        #pragma unroll
        for (int off = 8; off; off >>= 1) {
            float    ob1 = __shfl_xor(b1[r], off, 64);
            float    ob2 = __shfl_xor(b2[r], off, 64);
            unsigned oi1 = (unsigned)__shfl_xor((int)i1[r], off, 64);
            if (ob1 < b1[r] || (ob1 == b1[r] && oi1 < i1[r])) {
                b2[r] = fminf(b1[r], ob2);
                b1[r] = ob1; i1[r] = oi1;
            } else {
                b2[r] = fminf(b2[r], ob1);
            }
        }
        if (lr == 0) {
            long row = r0 + w * 16 + lg * 4 + r;
            pb[row * 4 + nb]  = make_float2(b1[r], b2[r]);
            pbi[row * 4 + nb] = (unsigned)c0 + i1[r];
        }
    }
}

// ---------- finalize: merge 4 N-block partials, flag rescues ----------
__global__ __launch_bounds__(256) void finalize_kernel(
    const float2* __restrict__ pb, const unsigned* __restrict__ pbi,
    unsigned* __restrict__ codes, float* __restrict__ idx_out,
    unsigned* __restrict__ meta, unsigned* __restrict__ rlist) {
    int row = blockIdx.x * 256 + threadIdx.x;
    float B1 = 3.4e38f, B2 = 3.4e38f; unsigned I1 = 0;
    #pragma unroll
    for (int nb = 0; nb < 4; ++nb) {   // ascending nb: strict < keeps first index
        float2  p = pb[row * 4 + nb];
        unsigned i = pbi[row * 4 + nb];
        if (p.x < B1) { B2 = fminf(B1, p.y); B1 = p.x; I1 = i; }
        else          { B2 = fminf(B2, p.x); }
    }
    if (B2 - B1 <= RESCUE_MARGIN) {
        codes[row] = I1 | 0x80000000u;
        rlist[atomicAdd(meta, 1u)] = (unsigned)row;
    } else {
        codes[row] = I1;
        idx_out[row] = (float)I1;
    }
}

// ---------- rescue: exact fp32 argmin for flagged rows; writes z_q+idx ----------
__global__ __launch_bounds__(256) void rescue_kernel(
    const float* __restrict__ z, const float* __restrict__ emb,
    const float* __restrict__ enorm, const unsigned* __restrict__ meta,
    const unsigned* __restrict__ rlist, float* __restrict__ zq,
    float* __restrict__ idx_out) {
    __shared__ float zrow[C_DIM];
    __shared__ float rd[256];
    __shared__ unsigned rix[256];
    const unsigned cnt = meta[0];
    for (unsigned li = blockIdx.x; li < cnt; li += gridDim.x) {
        unsigned row = rlist[li];
        __syncthreads();
        if (threadIdx.x < 64) {
            float4 v = reinterpret_cast<const float4*>(z)[(size_t)row * 64 + threadIdx.x];
            reinterpret_cast<float4*>(zrow)[threadIdx.x] = v;
        }
        __syncthreads();
        float bd = 3.4e38f; unsigned bi = 0;
        for (int c = threadIdx.x; c < NCODE; c += 256) {
            float acc = 0.f;
            const float4* ep = reinterpret_cast<const float4*>(emb + (size_t)c * C_DIM);
            const float4* zp = reinterpret_cast<const float4*>(zrow);
            #pragma unroll 8
            for (int k = 0; k < 64; ++k) {
                float4 e4 = ep[k], z4 = zp[k];
                acc = fmaf(z4.x, e4.x, acc); acc = fmaf(z4.y, e4.y, acc);
                acc = fmaf(z4.z, e4.z, acc); acc = fmaf(z4.w, e4.w, acc);
            }
            float d = fmaf(-2.f, acc, enorm[c]);
            if (d < bd) { bd = d; bi = (unsigned)c; }
        }
        rd[threadIdx.x] = bd; rix[threadIdx.x] = bi;
        __syncthreads();
        for (int s = 128; s; s >>= 1) {
            if (threadIdx.x < (unsigned)s) {
                float od = rd[threadIdx.x + s]; unsigned oi = rix[threadIdx.x + s];
                if (od < rd[threadIdx.x] ||
                    (od == rd[threadIdx.x] && oi < rix[threadIdx.x])) {
                    rd[threadIdx.x] = od; rix[threadIdx.x] = oi;
                }
            }
            __syncthreads();
        }
        unsigned code = rix[0];
        if (threadIdx.x < 64) {
            float4 v = reinterpret_cast<const float4*>(emb)[(size_t)code * 64 + threadIdx.x];
            reinterpret_cast<float4*>(zq)[(size_t)row * 64 + threadIdx.x] = v;
        }
        if (threadIdx.x == 0) idx_out[row] = (float)code;
    }
}

// ---------- gather: z_q for non-flagged rows ----------
__global__ __launch_bounds__(256) void gather_kernel(
    const float* __restrict__ emb, const unsigned* __restrict__ codes,
    float* __restrict__ zq) {
    const long row = (long)blockIdx.x * 4 + (threadIdx.x >> 6);
    const int lane = threadIdx.x & 63;
    unsigned c = codes[row];
    if (c & 0x80000000u) return;   // rescue wrote this row
    float4 v = reinterpret_cast<const float4*>(emb)[(size_t)c * 64 + lane];
    reinterpret_cast<float4*>(zq)[row * 64 + lane] = v;
}

extern "C" void kernel_launch(void* const* d_in, const int* in_sizes, int n_in,
                              void* d_out, int out_size, void* d_ws, size_t ws_size,
                              hipStream_t stream) {
    const float* z   = (const float*)d_in[0];
    const float* emb = (const float*)d_in[1];
    const int n = in_sizes[0] / C_DIM;   // 32768

    float* zq      = (float*)d_out;
    float* idx_out = zq + (size_t)n * C_DIM;

    char* ws = (char*)d_ws;
    float*          enorm = (float*)(ws + WS_ENORM);
    unsigned*       meta  = (unsigned*)(ws + WS_META);
    unsigned*       rlist = (unsigned*)(ws + WS_RLIST);
    unsigned*       codes = (unsigned*)(ws + WS_CODES);
    unsigned short* ehi   = (unsigned short*)(ws + WS_EHI);
    float2*         pb    = (float2*)(ws + WS_PB);
    unsigned*       pbi   = (unsigned*)(ws + WS_PBI);

    prep_kernel<<<256, 256, 0, stream>>>(emb, ehi, enorm, meta);
    vq_main_kernel<<<(n / 128) * 4, 512, 0, stream>>>(z, ehi, enorm, pb, pbi);
    finalize_kernel<<<n / 256, 256, 0, stream>>>(pb, pbi, codes, idx_out, meta, rlist);
    rescue_kernel<<<128, 256, 0, stream>>>(z, emb, enorm, meta, rlist, zq, idx_out);
    gather_kernel<<<n / 4, 256, 0, stream>>>(emb, codes, zq);
}

// Round 5
// 147.346 us; speedup vs baseline: 2.7390x; 2.7390x over previous
//
#include <hip/hip_runtime.h>

#define C_DIM 256
#define NCODE 1024
#define RESCUE_MARGIN 0.02f

typedef __bf16 bf16x8 __attribute__((ext_vector_type(8)));
typedef float f32x4 __attribute__((ext_vector_type(4)));

// ws layout (byte offsets), ~5 MB total
#define WS_ENORM 0          // f32[1024]
#define WS_META  4096       // u32
#define WS_RLIST 8192       // u32[32768]
#define WS_CODES 139264     // u32[32768] (bit31 = rescue flag)
#define WS_BP    270336     // bf16 B'[1024][768] pre-swizzled (1.5 MB)
#define WS_PB    1843200    // float2[32768][8] (b1,b2)
#define WS_PBI   3940352    // u32[32768][8]

#define GLOAD_LDS16(g, s)                                                            \
  __builtin_amdgcn_global_load_lds(                                                  \
      (const __attribute__((address_space(1))) unsigned int*)(g),                    \
      (__attribute__((address_space(3))) unsigned int*)(s), 16, 0, 0)

__device__ __forceinline__ void bf16split(float x, unsigned short& h, unsigned short& l) {
    unsigned u  = __float_as_uint(x);
    unsigned rh = (u + 0x7FFFu + ((u >> 16) & 1u)) & 0xFFFF0000u;   // RNE to bf16
    float    lf = x - __uint_as_float(rh);                          // exact
    unsigned ul = __float_as_uint(lf);
    h = (unsigned short)(rh >> 16);
    l = (unsigned short)((ul + 0x7FFFu + ((ul >> 16) & 1u)) >> 16);
}

// ---------- prep_misc: enorm (fp32, wave-reduce) + meta reset ----------
__global__ __launch_bounds__(256) void prep_misc_kernel(const float* __restrict__ emb,
                                                        float* __restrict__ enorm,
                                                        unsigned* __restrict__ meta) {
    int gid = blockIdx.x * 256 + threadIdx.x;
    if (gid == 0) meta[0] = 0u;
    int row = gid >> 6, lane = gid & 63;
    float4 v = reinterpret_cast<const float4*>(emb)[(size_t)row * 64 + lane];
    float s = v.x * v.x + v.y * v.y + v.z * v.z + v.w * v.w;
    #pragma unroll
    for (int off = 32; off; off >>= 1) s += __shfl_xor(s, off, 64);
    if (lane == 0) enorm[row] = s;
}

// ---------- prep_b: B'[code][768] = [eh | el | eh], pre-swizzled ----------
// swizzle: global (code, chunk, s_pos) holds source col-group s_pos^(code&7)
__global__ __launch_bounds__(256) void prep_b_kernel(const float* __restrict__ emb,
                                                     unsigned short* __restrict__ bp) {
    int gid  = blockIdx.x * 256 + threadIdx.x;   // 1024 codes x 128 (96 used)
    int code = gid >> 7, g = gid & 127;
    if (g >= 96) return;
    int chunk = g >> 3, spos = g & 7;
    int ssrc  = spos ^ (code & 7);
    bool lo   = (chunk >= 4 && chunk < 8);
    const float* src = emb + (size_t)code * C_DIM + (chunk & 3) * 64 + ssrc * 8;
    unsigned short o[8];
    #pragma unroll
    for (int j = 0; j < 8; ++j) {
        unsigned short h, l;
        bf16split(src[j], h, l);
        o[j] = lo ? l : h;
    }
    uint4 pk;
    pk.x = (unsigned)o[0] | ((unsigned)o[1] << 16);
    pk.y = (unsigned)o[2] | ((unsigned)o[3] << 16);
    pk.z = (unsigned)o[4] | ((unsigned)o[5] << 16);
    pk.w = (unsigned)o[6] | ((unsigned)o[7] << 16);
    *reinterpret_cast<uint4*>(bp + (size_t)code * 768 + chunk * 64 + spos * 8) = pk;
}

// ---------- prep_z: A'[m][512] = [zh | zl], pre-swizzled, into d_out ----------
__global__ __launch_bounds__(256) void prep_z_kernel(const float* __restrict__ z,
                                                     unsigned short* __restrict__ ap) {
    int gid   = blockIdx.x * 256 + threadIdx.x;  // 32768 x 64
    int m     = gid >> 6, g = gid & 63;
    int chunk = g >> 3, spos = g & 7;            // chunk 0..7 (0-3 hi, 4-7 lo)
    int ssrc  = spos ^ (m & 7);
    bool lo   = chunk >= 4;
    const float* src = z + (size_t)m * C_DIM + (chunk & 3) * 64 + ssrc * 8;
    unsigned short o[8];
    #pragma unroll
    for (int j = 0; j < 8; ++j) {
        unsigned short h, l;
        bf16split(src[j], h, l);
        o[j] = lo ? l : h;
    }
    uint4 pk;
    pk.x = (unsigned)o[0] | ((unsigned)o[1] << 16);
    pk.y = (unsigned)o[2] | ((unsigned)o[3] << 16);
    pk.z = (unsigned)o[4] | ((unsigned)o[5] << 16);
    pk.w = (unsigned)o[6] | ((unsigned)o[7] << 16);
    *reinterpret_cast<uint4*>(ap + (size_t)m * 512 + chunk * 64 + spos * 8) = pk;
}

// ---------- main: 128x128-tile bf16 GEMM K'=768, m97 structure ----------
// grid 2048 = 256 mt x 8 nt; 256 thr (4 waves, 2x2); wave tile 64x64.
// K-chunks of 64: c 0-3 -> zh*eh, 4-7 -> zh*el, 8-11 -> zl*eh.
__global__ __launch_bounds__(256, 3) void vq_gemm_kernel(
    const unsigned short* __restrict__ ap, const unsigned short* __restrict__ bp,
    const float* __restrict__ enorm, float2* __restrict__ pb,
    unsigned* __restrict__ pbi) {
    __shared__ alignas(16) unsigned short Abuf[128 * 64];  // 16 KB
    __shared__ alignas(16) unsigned short Bbuf[128 * 64];  // 16 KB
    __shared__ float en_s[128];
    __shared__ float rv1[128][2], rv2[128][2];
    __shared__ int   rixs[128][2];

    const int t  = threadIdx.x;
    const int wv = t >> 6, l = t & 63;
    const int lr = l & 15, lg = l >> 4;
    const int wm = wv >> 1, wn = wv & 1;
    const int bid = blockIdx.x;
    const int nt  = bid & 7;
    const long r0 = (long)(bid >> 3) * 128;
    const int  c0 = nt * 128;

    if (t < 128) en_s[t] = enorm[c0 + t];

    f32x4 acc[4][4];
    #pragma unroll
    for (int mf = 0; mf < 4; ++mf)
        #pragma unroll
        for (int nf = 0; nf < 4; ++nf) acc[mf][nf] = (f32x4){0.f, 0.f, 0.f, 0.f};

    const int srow = (l >> 3);        // staging row-in-q
    const int ss   = l & 7;           // staging col-group

    for (int c = 0; c < 12; ++c) {
        const int kA = (c & 3) * 64 + (c & 8) * 32;   // A' col base (hi/hi/lo)
        const int kB = c * 64;                        // B' col base
        __syncthreads();   // prior chunk's frag reads done
        #pragma unroll
        for (int i = 0; i < 4; ++i) {
            int q = wv * 4 + i;                       // 0..15; wave-uniform
            int arow = q * 8 + srow;                  // 0..127
            const unsigned short* ga = ap + (size_t)(r0 + arow) * 512 + kA + ss * 8;
            GLOAD_LDS16(ga, Abuf + q * 512);
            const unsigned short* gb = bp + (size_t)(c0 + arow) * 768 + kB + ss * 8;
            GLOAD_LDS16(gb, Bbuf + q * 512);
        }
        __syncthreads();   // staged data visible

        #pragma unroll
        for (int ks = 0; ks < 2; ++ks) {
            const int sA = ((ks << 2) | lg) ^ (lr & 7);   // swizzled col-group
            bf16x8 a[4], b[4];
            #pragma unroll
            for (int mf = 0; mf < 4; ++mf)
                a[mf] = *reinterpret_cast<const bf16x8*>(
                    &Abuf[(wm * 64 + mf * 16 + lr) * 64 + sA * 8]);
            #pragma unroll
            for (int nf = 0; nf < 4; ++nf)
                b[nf] = *reinterpret_cast<const bf16x8*>(
                    &Bbuf[(wn * 64 + nf * 16 + lr) * 64 + sA * 8]);
            #pragma unroll
            for (int mf = 0; mf < 4; ++mf)
                #pragma unroll
                for (int nf = 0; nf < 4; ++nf)
                    acc[mf][nf] = __builtin_amdgcn_mfma_f32_16x16x32_bf16(
                        a[mf], b[nf], acc[mf][nf], 0, 0, 0);
        }
    }

    // epilogue: d = enorm - 2*dot, per-row top-2, lr-shuffle merge
    #pragma unroll
    for (int mf = 0; mf < 4; ++mf) {
        #pragma unroll
        for (int r = 0; r < 4; ++r) {
            float b1 = 3.4e38f, b2 = 3.4e38f; int i1 = 0;
            #pragma unroll
            for (int nf = 0; nf < 4; ++nf) {
                int   cl = wn * 64 + nf * 16 + lr;
                float d  = fmaf(-2.f, acc[mf][nf][r], en_s[cl]);
                if (d < b1) { b2 = b1; b1 = d; i1 = cl; }
                else if (d < b2) { b2 = d; }
            }
            #pragma unroll
            for (int off = 8; off; off >>= 1) {
                float ob1 = __shfl_xor(b1, off, 64);
                float ob2 = __shfl_xor(b2, off, 64);
                int   oi1 = __shfl_xor(i1, off, 64);
                if (ob1 < b1 || (ob1 == b1 && oi1 < i1)) {
                    b2 = fminf(b1, ob2); b1 = ob1; i1 = oi1;
                } else {
                    b2 = fminf(b2, ob1);
                }
            }
            if (lr == 0) {
                int rowl = wm * 64 + mf * 16 + lg * 4 + r;
                rv1[rowl][wn] = b1; rv2[rowl][wn] = b2; rixs[rowl][wn] = i1;
            }
        }
    }
    __syncthreads();
    if (t < 128) {
        float B1 = rv1[t][0], B2 = rv2[t][0]; int I1 = rixs[t][0];
        float o1 = rv1[t][1], o2 = rv2[t][1]; int O1 = rixs[t][1];
        if (o1 < B1) { B2 = fminf(B1, o2); B1 = o1; I1 = O1; }
        else         { B2 = fminf(B2, o1); }
        pb [(r0 + t) * 8 + nt] = make_float2(B1, B2);
        pbi[(r0 + t) * 8 + nt] = (unsigned)(c0 + I1);
    }
}

// ---------- finalize: merge 8 slots, flag rescues, write idx ----------
__global__ __launch_bounds__(256) void finalize_kernel(
    const float2* __restrict__ pb, const unsigned* __restrict__ pbi,
    unsigned* __restrict__ codes, float* __restrict__ idx_out,
    unsigned* __restrict__ meta, unsigned* __restrict__ rlist) {
    int row = blockIdx.x * 256 + threadIdx.x;
    float B1 = 3.4e38f, B2 = 3.4e38f; unsigned I1 = 0;
    #pragma unroll
    for (int s = 0; s < 8; ++s) {   // ascending slot = ascending code range
        float2   p = pb [row * 8 + s];
        unsigned i = pbi[row * 8 + s];
        if (p.x < B1) { B2 = fminf(B1, p.y); B1 = p.x; I1 = i; }
        else          { B2 = fminf(B2, p.x); }
    }
    if (B2 - B1 <= RESCUE_MARGIN) {
        codes[row] = I1 | 0x80000000u;
        rlist[atomicAdd(meta, 1u)] = (unsigned)row;
    } else {
        codes[row] = I1;
        idx_out[row] = (float)I1;
    }
}

// ---------- rescue: exact fp32 argmin (4 interleaved chains) ----------
__global__ __launch_bounds__(256) void rescue_kernel(
    const float* __restrict__ z, const float* __restrict__ emb,
    const float* __restrict__ enorm, const unsigned* __restrict__ meta,
    const unsigned* __restrict__ rlist, float* __restrict__ zq,
    float* __restrict__ idx_out) {
    __shared__ float zrow[C_DIM];
    __shared__ float rd[256];
    __shared__ unsigned rix[256];
    const unsigned cnt = meta[0];
    for (unsigned li = blockIdx.x; li < cnt; li += gridDim.x) {
        unsigned row = rlist[li];
        __syncthreads();
        if (threadIdx.x < 64) {
            float4 v = reinterpret_cast<const float4*>(z)[(size_t)row * 64 + threadIdx.x];
            reinterpret_cast<float4*>(zrow)[threadIdx.x] = v;
        }
        __syncthreads();
        const int c = threadIdx.x;
        float a0 = 0.f, a1 = 0.f, a2 = 0.f, a3 = 0.f;
        const float4* zp = reinterpret_cast<const float4*>(zrow);
        const float4* e0 = reinterpret_cast<const float4*>(emb + (size_t)(c)       * C_DIM);
        const float4* e1 = reinterpret_cast<const float4*>(emb + (size_t)(c + 256) * C_DIM);
        const float4* e2 = reinterpret_cast<const float4*>(emb + (size_t)(c + 512) * C_DIM);
        const float4* e3 = reinterpret_cast<const float4*>(emb + (size_t)(c + 768) * C_DIM);
        #pragma unroll 8
        for (int k = 0; k < 64; ++k) {
            float4 z4 = zp[k];
            float4 f0 = e0[k], f1 = e1[k], f2 = e2[k], f3 = e3[k];
            a0 = fmaf(z4.x, f0.x, a0); a0 = fmaf(z4.y, f0.y, a0);
            a0 = fmaf(z4.z, f0.z, a0); a0 = fmaf(z4.w, f0.w, a0);
            a1 = fmaf(z4.x, f1.x, a1); a1 = fmaf(z4.y, f1.y, a1);
            a1 = fmaf(z4.z, f1.z, a1); a1 = fmaf(z4.w, f1.w, a1);
            a2 = fmaf(z4.x, f2.x, a2); a2 = fmaf(z4.y, f2.y, a2);
            a2 = fmaf(z4.z, f2.z, a2); a2 = fmaf(z4.w, f2.w, a2);
            a3 = fmaf(z4.x, f3.x, a3); a3 = fmaf(z4.y, f3.y, a3);
            a3 = fmaf(z4.z, f3.z, a3); a3 = fmaf(z4.w, f3.w, a3);
        }
        float d0 = fmaf(-2.f, a0, enorm[c]);
        float d1 = fmaf(-2.f, a1, enorm[c + 256]);
        float d2 = fmaf(-2.f, a2, enorm[c + 512]);
        float d3 = fmaf(-2.f, a3, enorm[c + 768]);
        float bd = d0; unsigned bi = (unsigned)c;
        if (d1 < bd) { bd = d1; bi = (unsigned)(c + 256); }
        if (d2 < bd) { bd = d2; bi = (unsigned)(c + 512); }
        if (d3 < bd) { bd = d3; bi = (unsigned)(c + 768); }
        rd[threadIdx.x] = bd; rix[threadIdx.x] = bi;
        __syncthreads();
        for (int s = 128; s; s >>= 1) {
            if (threadIdx.x < (unsigned)s) {
                float od = rd[threadIdx.x + s]; unsigned oi = rix[threadIdx.x + s];
                if (od < rd[threadIdx.x] ||
                    (od == rd[threadIdx.x] && oi < rix[threadIdx.x])) {
                    rd[threadIdx.x] = od; rix[threadIdx.x] = oi;
                }
            }
            __syncthreads();
        }
        unsigned code = rix[0];
        if (threadIdx.x < 64) {
            float4 v = reinterpret_cast<const float4*>(emb)[(size_t)code * 64 + threadIdx.x];
            reinterpret_cast<float4*>(zq)[(size_t)row * 64 + threadIdx.x] = v;
        }
        if (threadIdx.x == 0) idx_out[row] = (float)code;
    }
}

// ---------- gather: z_q for non-flagged rows ----------
__global__ __launch_bounds__(256) void gather_kernel(
    const float* __restrict__ emb, const unsigned* __restrict__ codes,
    float* __restrict__ zq) {
    const long row = (long)blockIdx.x * 4 + (threadIdx.x >> 6);
    const int lane = threadIdx.x & 63;
    unsigned c = codes[row];
    if (c & 0x80000000u) return;   // rescue writes this row
    float4 v = reinterpret_cast<const float4*>(emb)[(size_t)c * 64 + lane];
    reinterpret_cast<float4*>(zq)[row * 64 + lane] = v;
}

extern "C" void kernel_launch(void* const* d_in, const int* in_sizes, int n_in,
                              void* d_out, int out_size, void* d_ws, size_t ws_size,
                              hipStream_t stream) {
    const float* z   = (const float*)d_in[0];
    const float* emb = (const float*)d_in[1];
    const int n = in_sizes[0] / C_DIM;   // 32768

    float* zq      = (float*)d_out;
    float* idx_out = zq + (size_t)n * C_DIM;

    char* ws = (char*)d_ws;
    float*          enorm = (float*)(ws + WS_ENORM);
    unsigned*       meta  = (unsigned*)(ws + WS_META);
    unsigned*       rlist = (unsigned*)(ws + WS_RLIST);
    unsigned*       codes = (unsigned*)(ws + WS_CODES);
    unsigned short* bp    = (unsigned short*)(ws + WS_BP);
    float2*         pb    = (float2*)(ws + WS_PB);
    unsigned*       pbi   = (unsigned*)(ws + WS_PBI);

    // A' (32768x512 bf16 = 33.55 MB) aliases the z_q output region: it is
    // fully consumed by vq_gemm before rescue/gather overwrite it.
    unsigned short* ap = (unsigned short*)d_out;

    prep_misc_kernel<<<256, 256, 0, stream>>>(emb, enorm, meta);
    prep_b_kernel<<<512, 256, 0, stream>>>(emb, bp);
    prep_z_kernel<<<8192, 256, 0, stream>>>(z, ap);
    vq_gemm_kernel<<<2048, 256, 0, stream>>>(ap, bp, enorm, pb, pbi);
    finalize_kernel<<<n / 256, 256, 0, stream>>>(pb, pbi, codes, idx_out, meta, rlist);
    rescue_kernel<<<256, 256, 0, stream>>>(z, emb, enorm, meta, rlist, zq, idx_out);
    gather_kernel<<<n / 4, 256, 0, stream>>>(emb, codes, zq);
}

// Round 6
// 135.950 us; speedup vs baseline: 2.9686x; 1.0838x over previous
//
#include <hip/hip_runtime.h>

#define C_DIM 256
#define NCODE 1024
#define MARGIN 0.02f

typedef __bf16 bf16x8 __attribute__((ext_vector_type(8)));
typedef float f32x4 __attribute__((ext_vector_type(4)));

// ws layout (byte offsets)
#define WS_ENORM 0         // f32[1024]
#define WS_META  4096      // u32 rescue count
#define WS_RLIST 8192      // u32[32768]
#define WS_BP    139264    // u16[32 chunks][16384]  (1 MB) pre-fragmented B'

#define GLOAD_LDS16(g, s)                                                            \
  __builtin_amdgcn_global_load_lds(                                                  \
      (const __attribute__((address_space(1))) unsigned int*)(g),                    \
      (__attribute__((address_space(3))) unsigned int*)(s), 16, 0, 0)

__device__ __forceinline__ void bf16split(float x, unsigned short& h, unsigned short& l) {
    unsigned u  = __float_as_uint(x);
    unsigned rh = (u + 0x7FFFu + ((u >> 16) & 1u)) & 0xFFFF0000u;   // RNE to bf16
    float    lf = x - __uint_as_float(rh);                          // exact
    unsigned ul = __float_as_uint(lf);
    h = (unsigned short)(rh >> 16);
    l = (unsigned short)((ul + 0x7FFFu + ((ul >> 16) & 1u)) >> 16);
}

// ---------- prep_misc: enorm (fp32 wave-reduce) + meta reset ----------
__global__ __launch_bounds__(256) void prep_misc_kernel(const float* __restrict__ emb,
                                                        float* __restrict__ enorm,
                                                        unsigned* __restrict__ meta) {
    int gid = blockIdx.x * 256 + threadIdx.x;
    if (gid == 0) meta[0] = 0u;
    int row = gid >> 6, lane = gid & 63;
    float4 v = reinterpret_cast<const float4*>(emb)[(size_t)row * 64 + lane];
    float s = v.x * v.x + v.y * v.y + v.z * v.z + v.w * v.w;
    #pragma unroll
    for (int off = 32; off; off >>= 1) s += __shfl_xor(s, off, 64);
    if (lane == 0) enorm[row] = s;
}

// ---------- prep_b: split emb -> B' in MFMA-frag order ----------
// chunk = 32 codes. frag f = side*16 + nf*8 + kc (side 0=hi,1=lo; nf=code-16-
// group; kc=k/32). Within frag: lane (lg*16+lr) holds e[nf*16+lr][kc*32+lg*8..+7].
__global__ __launch_bounds__(256) void prep_b_kernel(const float* __restrict__ emb,
                                                     unsigned short* __restrict__ bp) {
    int tid = blockIdx.x * 256 + threadIdx.x;   // 32768 = 1024 codes x 32
    int j   = tid >> 5;                         // code
    int u   = tid & 31;
    int kc  = u >> 2, lg = u & 3;
    const float* src = emb + (size_t)j * C_DIM + kc * 32 + lg * 8;
    float4 v0 = *reinterpret_cast<const float4*>(src);
    float4 v1 = *reinterpret_cast<const float4*>(src + 4);
    float vs[8] = {v0.x, v0.y, v0.z, v0.w, v1.x, v1.y, v1.z, v1.w};
    unsigned short h[8], l[8];
    #pragma unroll
    for (int k = 0; k < 8; ++k) bf16split(vs[k], h[k], l[k]);
    int chunk = j >> 5, nf = (j >> 4) & 1, lr = j & 15;
    int lane  = lg * 16 + lr;
    size_t base = (size_t)chunk * 16384 + (size_t)(nf * 8 + kc) * 512 + lane * 8;
    uint4 hp, lp;
    hp.x = (unsigned)h[0] | ((unsigned)h[1] << 16);
    hp.y = (unsigned)h[2] | ((unsigned)h[3] << 16);
    hp.z = (unsigned)h[4] | ((unsigned)h[5] << 16);
    hp.w = (unsigned)h[6] | ((unsigned)h[7] << 16);
    lp.x = (unsigned)l[0] | ((unsigned)l[1] << 16);
    lp.y = (unsigned)l[2] | ((unsigned)l[3] << 16);
    lp.z = (unsigned)l[4] | ((unsigned)l[5] << 16);
    lp.w = (unsigned)l[6] | ((unsigned)l[7] << 16);
    *reinterpret_cast<uint4*>(bp + base)             = hp;   // hi side
    *reinterpret_cast<uint4*>(bp + base + 16 * 512)  = lp;   // lo side
}

// ---------- main: fused 3-pass split-bf16 MFMA + argmin + idx + gather ----------
// 256 blocks x 512 thr (8 waves = 4 row-groups x 2 code-halves).
// Block: 128 rows x all 1024 codes, K=256. A (z hi/lo) in registers.
// B' chunks (32 codes) double-buffered in LDS via global_load_lds + vmcnt(4).
__global__ __launch_bounds__(512, 2) void vq_main_kernel(
    const float* __restrict__ z, const unsigned short* __restrict__ bp,
    const float* __restrict__ emb, const float* __restrict__ enorm,
    float* __restrict__ zq, float* __restrict__ idx_out,
    unsigned* __restrict__ meta, unsigned* __restrict__ rlist) {
    __shared__ alignas(16) unsigned short Bds[2][16384];   // 64 KB (2 x 32-code chunk)
    __shared__ float en_s[NCODE];
    __shared__ float mv1[128][2], mv2[128][2];
    __shared__ unsigned mi[128][2];
    __shared__ unsigned codes_l[128];

    const int t    = threadIdx.x;
    const int w    = t >> 6;       // wave 0..7
    const int lane = t & 63;
    const int lr   = lane & 15, lg = lane >> 4;
    const int wm   = w >> 1;       // row-group 0..3 (32 rows each)
    const int ng   = w & 1;        // code-half within chunk (16 codes)
    const long r0  = (long)blockIdx.x * 128;

    // stage chunk 0 (4 gload_lds per thread; frag f = round*8 + w)
    {
        const unsigned short* src = bp;
        #pragma unroll
        for (int round = 0; round < 4; ++round) {
            int f = round * 8 + w;
            GLOAD_LDS16(src + (size_t)f * 512 + lane * 8, &Bds[0][f * 512]);
        }
    }
    en_s[t]       = enorm[t];
    en_s[t + 512] = enorm[t + 512];

    // A: load my 32 rows' z, split to bf16 hi/lo fragments (128 VGPR)
    bf16x8 ah[2][8], al[2][8];
    #pragma unroll
    for (int m = 0; m < 2; ++m) {
        const float* zr = z + (r0 + wm * 32 + m * 16 + lr) * C_DIM + lg * 8;
        #pragma unroll
        for (int kc = 0; kc < 8; ++kc) {
            float4 v0 = *reinterpret_cast<const float4*>(zr + kc * 32);
            float4 v1 = *reinterpret_cast<const float4*>(zr + kc * 32 + 4);
            float vs[8] = {v0.x, v0.y, v0.z, v0.w, v1.x, v1.y, v1.z, v1.w};
            unsigned short hv[8], lv[8];
            #pragma unroll
            for (int jj = 0; jj < 8; ++jj) bf16split(vs[jj], hv[jj], lv[jj]);
            unsigned hp[4] = {
                (unsigned)hv[0] | ((unsigned)hv[1] << 16), (unsigned)hv[2] | ((unsigned)hv[3] << 16),
                (unsigned)hv[4] | ((unsigned)hv[5] << 16), (unsigned)hv[6] | ((unsigned)hv[7] << 16)};
            unsigned lp[4] = {
                (unsigned)lv[0] | ((unsigned)lv[1] << 16), (unsigned)lv[2] | ((unsigned)lv[3] << 16),
                (unsigned)lv[4] | ((unsigned)lv[5] << 16), (unsigned)lv[6] | ((unsigned)lv[7] << 16)};
            ah[m][kc] = __builtin_bit_cast(bf16x8, *reinterpret_cast<uint4*>(hp));
            al[m][kc] = __builtin_bit_cast(bf16x8, *reinterpret_cast<uint4*>(lp));
        }
    }

    float b1[2][4], b2[2][4]; unsigned i1[2][4];
    #pragma unroll
    for (int m = 0; m < 2; ++m)
        #pragma unroll
        for (int r = 0; r < 4; ++r) { b1[m][r] = 3.4e38f; b2[m][r] = 3.4e38f; i1[m][r] = 0; }

    for (int c = 0; c < 32; ++c) {
        const int cur = c & 1;
        __syncthreads();   // everyone done reading buf[cur^1] (chunk c-1)
        if (c < 31) {
            const unsigned short* src = bp + (size_t)(c + 1) * 16384;
            #pragma unroll
            for (int round = 0; round < 4; ++round) {
                int f = round * 8 + w;
                GLOAD_LDS16(src + (size_t)f * 512 + lane * 8, &Bds[cur ^ 1][f * 512]);
            }
            asm volatile("s_waitcnt vmcnt(4)" ::: "memory");   // chunk c done; c+1 in flight
        } else {
            asm volatile("s_waitcnt vmcnt(0)" ::: "memory");
        }
        __syncthreads();   // chunk c visible to all waves

        // 6 independent accumulator chains (hh/hl/lh x 2 m-frags)
        f32x4 hh0 = {0.f,0.f,0.f,0.f}, hh1 = {0.f,0.f,0.f,0.f};
        f32x4 hl0 = {0.f,0.f,0.f,0.f}, hl1 = {0.f,0.f,0.f,0.f};
        f32x4 lh0 = {0.f,0.f,0.f,0.f}, lh1 = {0.f,0.f,0.f,0.f};
        const unsigned short* bb = &Bds[cur][(ng * 8) * 512 + lane * 8];
        #pragma unroll
        for (int kc = 0; kc < 8; ++kc) {
            bf16x8 bh = *reinterpret_cast<const bf16x8*>(bb + kc * 512);
            bf16x8 bl = *reinterpret_cast<const bf16x8*>(bb + (16 + kc) * 512);
            hh0 = __builtin_amdgcn_mfma_f32_16x16x32_bf16(ah[0][kc], bh, hh0, 0, 0, 0);
            hh1 = __builtin_amdgcn_mfma_f32_16x16x32_bf16(ah[1][kc], bh, hh1, 0, 0, 0);
            lh0 = __builtin_amdgcn_mfma_f32_16x16x32_bf16(al[0][kc], bh, lh0, 0, 0, 0);
            lh1 = __builtin_amdgcn_mfma_f32_16x16x32_bf16(al[1][kc], bh, lh1, 0, 0, 0);
            hl0 = __builtin_amdgcn_mfma_f32_16x16x32_bf16(ah[0][kc], bl, hl0, 0, 0, 0);
            hl1 = __builtin_amdgcn_mfma_f32_16x16x32_bf16(ah[1][kc], bl, hl1, 0, 0, 0);
        }

        const float    en   = en_s[c * 32 + ng * 16 + lr];
        const unsigned code = (unsigned)(c * 32 + ng * 16 + lr);   // ascends with c
        #pragma unroll
        for (int r = 0; r < 4; ++r) {
            float d0 = fmaf(-2.f, hh0[r] + hl0[r] + lh0[r], en);
            if (d0 < b1[0][r]) { b2[0][r] = b1[0][r]; b1[0][r] = d0; i1[0][r] = code; }
            else if (d0 < b2[0][r]) { b2[0][r] = d0; }
            float d1 = fmaf(-2.f, hh1[r] + hl1[r] + lh1[r], en);
            if (d1 < b1[1][r]) { b2[1][r] = b1[1][r]; b1[1][r] = d1; i1[1][r] = code; }
            else if (d1 < b2[1][r]) { b2[1][r] = d1; }
        }
    }

    // cross-lane (lr) top-2 merge, then cross-ng merge via LDS
    #pragma unroll
    for (int m = 0; m < 2; ++m)
        #pragma unroll
        for (int r = 0; r < 4; ++r) {
            float v1 = b1[m][r], v2 = b2[m][r]; unsigned j1 = i1[m][r];
            #pragma unroll
            for (int off = 8; off; off >>= 1) {
                float    ov1 = __shfl_xor(v1, off, 64);
                float    ov2 = __shfl_xor(v2, off, 64);
                unsigned oj1 = (unsigned)__shfl_xor((int)j1, off, 64);
                if (ov1 < v1 || (ov1 == v1 && oj1 < j1)) {
                    v2 = fminf(v1, ov2); v1 = ov1; j1 = oj1;
                } else {
                    v2 = fminf(v2, ov1);
                }
            }
            if (lr == 0) {
                int rowl = wm * 32 + m * 16 + lg * 4 + r;
                mv1[rowl][ng] = v1; mv2[rowl][ng] = v2; mi[rowl][ng] = j1;
            }
        }
    __syncthreads();
    if (t < 128) {
        float B1 = mv1[t][0], B2 = mv2[t][0]; unsigned I1 = mi[t][0];
        float o1 = mv1[t][1], o2 = mv2[t][1]; unsigned O1 = mi[t][1];
        if (o1 < B1 || (o1 == B1 && O1 < I1)) { B2 = fminf(B1, o2); B1 = o1; I1 = O1; }
        else                                  { B2 = fminf(B2, o1); }
        long row = r0 + t;
        idx_out[row] = (float)I1;
        codes_l[t]   = I1;
        if (B2 - B1 <= MARGIN) rlist[atomicAdd(meta, 1u)] = (unsigned)row;
    }
    __syncthreads();

    // fused gather: 4 threads per row, 16 float4 each (emb rows L2-resident)
    {
        int rowl = t >> 2, q = t & 3;
        unsigned code = codes_l[rowl];
        const float4* ep = reinterpret_cast<const float4*>(emb) + (size_t)code * 64 + q * 16;
        float4*       op = reinterpret_cast<float4*>(zq) + ((size_t)(r0 + rowl)) * 64 + q * 16;
        #pragma unroll
        for (int jj = 0; jj < 16; ++jj) op[jj] = ep[jj];
    }
}

// ---------- rescue: exact fp32 argmin for flagged rows; writes z_q+idx ----------
__global__ __launch_bounds__(256) void rescue_kernel(
    const float* __restrict__ z, const float* __restrict__ emb,
    const float* __restrict__ enorm, const unsigned* __restrict__ meta,
    const unsigned* __restrict__ rlist, float* __restrict__ zq,
    float* __restrict__ idx_out) {
    __shared__ float zrow[C_DIM];
    __shared__ float rd[256];
    __shared__ unsigned rix[256];
    const unsigned cnt = meta[0];
    for (unsigned li = blockIdx.x; li < cnt; li += gridDim.x) {
        unsigned row = rlist[li];
        __syncthreads();
        if (threadIdx.x < 64) {
            float4 v = reinterpret_cast<const float4*>(z)[(size_t)row * 64 + threadIdx.x];
            reinterpret_cast<float4*>(zrow)[threadIdx.x] = v;
        }
        __syncthreads();
        const int c = threadIdx.x;
        float a0 = 0.f, a1 = 0.f, a2 = 0.f, a3 = 0.f;
        const float4* zp = reinterpret_cast<const float4*>(zrow);
        const float4* e0 = reinterpret_cast<const float4*>(emb + (size_t)(c)       * C_DIM);
        const float4* e1 = reinterpret_cast<const float4*>(emb + (size_t)(c + 256) * C_DIM);
        const float4* e2 = reinterpret_cast<const float4*>(emb + (size_t)(c + 512) * C_DIM);
        const float4* e3 = reinterpret_cast<const float4*>(emb + (size_t)(c + 768) * C_DIM);
        #pragma unroll 8
        for (int k = 0; k < 64; ++k) {
            float4 z4 = zp[k];
            float4 f0 = e0[k], f1 = e1[k], f2 = e2[k], f3 = e3[k];
            a0 = fmaf(z4.x, f0.x, a0); a0 = fmaf(z4.y, f0.y, a0);
            a0 = fmaf(z4.z, f0.z, a0); a0 = fmaf(z4.w, f0.w, a0);
            a1 = fmaf(z4.x, f1.x, a1); a1 = fmaf(z4.y, f1.y, a1);
            a1 = fmaf(z4.z, f1.z, a1); a1 = fmaf(z4.w, f1.w, a1);
            a2 = fmaf(z4.x, f2.x, a2); a2 = fmaf(z4.y, f2.y, a2);
            a2 = fmaf(z4.z, f2.z, a2); a2 = fmaf(z4.w, f2.w, a2);
            a3 = fmaf(z4.x, f3.x, a3); a3 = fmaf(z4.y, f3.y, a3);
            a3 = fmaf(z4.z, f3.z, a3); a3 = fmaf(z4.w, f3.w, a3);
        }
        float d0 = fmaf(-2.f, a0, enorm[c]);
        float d1 = fmaf(-2.f, a1, enorm[c + 256]);
        float d2 = fmaf(-2.f, a2, enorm[c + 512]);
        float d3 = fmaf(-2.f, a3, enorm[c + 768]);
        float bd = d0; unsigned bi = (unsigned)c;
        if (d1 < bd) { bd = d1; bi = (unsigned)(c + 256); }
        if (d2 < bd) { bd = d2; bi = (unsigned)(c + 512); }
        if (d3 < bd) { bd = d3; bi = (unsigned)(c + 768); }
        rd[threadIdx.x] = bd; rix[threadIdx.x] = bi;
        __syncthreads();
        for (int s = 128; s; s >>= 1) {
            if (threadIdx.x < (unsigned)s) {
                float od = rd[threadIdx.x + s]; unsigned oi = rix[threadIdx.x + s];
                if (od < rd[threadIdx.x] ||
                    (od == rd[threadIdx.x] && oi < rix[threadIdx.x])) {
                    rd[threadIdx.x] = od; rix[threadIdx.x] = oi;
                }
            }
            __syncthreads();
        }
        unsigned code = rix[0];
        if (threadIdx.x < 64) {
            float4 v = reinterpret_cast<const float4*>(emb)[(size_t)code * 64 + threadIdx.x];
            reinterpret_cast<float4*>(zq)[(size_t)row * 64 + threadIdx.x] = v;
        }
        if (threadIdx.x == 0) idx_out[row] = (float)code;
    }
}

extern "C" void kernel_launch(void* const* d_in, const int* in_sizes, int n_in,
                              void* d_out, int out_size, void* d_ws, size_t ws_size,
                              hipStream_t stream) {
    const float* z   = (const float*)d_in[0];
    const float* emb = (const float*)d_in[1];
    const int n = in_sizes[0] / C_DIM;   // 32768

    float* zq      = (float*)d_out;
    float* idx_out = zq + (size_t)n * C_DIM;

    char* ws = (char*)d_ws;
    float*          enorm = (float*)(ws + WS_ENORM);
    unsigned*       meta  = (unsigned*)(ws + WS_META);
    unsigned*       rlist = (unsigned*)(ws + WS_RLIST);
    unsigned short* bp    = (unsigned short*)(ws + WS_BP);

    prep_misc_kernel<<<256, 256, 0, stream>>>(emb, enorm, meta);
    prep_b_kernel<<<128, 256, 0, stream>>>(emb, bp);
    vq_main_kernel<<<n / 128, 512, 0, stream>>>(z, bp, emb, enorm, zq, idx_out,
                                                meta, rlist);
    rescue_kernel<<<256, 256, 0, stream>>>(z, emb, enorm, meta, rlist, zq, idx_out);
}